// Round 6
// baseline (2578.192 us; speedup 1.0000x reference)
//
#include <hip/hip_runtime.h>

// ---------------------------------------------------------------------------
// AGCN block: a/b 1x1 convs -> scores -> softmax(+A) -> z = x@att -> y = Wd@z
// N=64 C=64 T=256 V=25 S=3 OC=64 IC=32. fp32 (no fp32 MFMA) -> VALU-bound.
// R5 post-mortem: xv[64] hoist SPILLED (VGPR_Count=68 << needed ~120) ->
// occupancy 25%, K1 355us. R6: fuse s-loop into conv (fa/fb[3][16] named
// accumulators, xv[8] batches) = same 3x load cut, bounded ~120 VGPR.
// K3 reverted to R4 form (5 blk/CU needs <=102 VGPR).
// ---------------------------------------------------------------------------

#define NCHUNK    16                     // t-chunks per n in K1
#define ATT_OFF   0                      // [N][S][25][32] padded att
#define ATT_SZ    (64*3*25*32)           // 153600
#define PART_OFF  153600                 // [N][NCHUNK][S][625] score partials
#define PART_SZ   (64*NCHUNK*3*625)      // 1920000
#define WAT_OFF   (PART_OFF + PART_SZ)   // [S][C][IC]
#define WBT_OFF   (WAT_OFF + 3*64*32)    // [S][C][IC]
#define WDT_OFF   (WBT_OFF + 3*64*32)    // [S][C][OC]
#define ALPHA_OFF (WDT_OFF + 3*64*64)    // [OC]
#define BETA_OFF  (ALPHA_OFF + 64)       // [OC]

// --------------------------- K0: weight prep -------------------------------
__global__ __launch_bounds__(256) void k0_prep(
    float* __restrict__ wsf,
    const float* __restrict__ Wa, const float* __restrict__ Wb,
    const float* __restrict__ Wd, const float* __restrict__ bd,
    const float* __restrict__ gamma, const float* __restrict__ beta)
{
  int idx = blockIdx.x * 256 + threadIdx.x;
  if (idx < 6144) {                       // WaT/WbT: [s][c][i] <- [s][i][c]
    int s = idx / 2048, r = idx - s * 2048, c = r >> 5, i = r & 31;
    wsf[WAT_OFF + idx] = Wa[s * 2048 + i * 64 + c];
    wsf[WBT_OFF + idx] = Wb[s * 2048 + i * 64 + c];
  }
  if (idx < 12288) {                      // WdT: [s][c][o] <- [s][o][c]
    int s = idx / 4096, r = idx - s * 4096, c = r >> 6, o = r & 63;
    wsf[WDT_OFF + idx] = Wd[s * 4096 + o * 64 + c];
  }
  if (idx < 64) {                         // fused BN(inference) + bias-sum
    float al = gamma[idx] * rsqrtf(1.0f + 1e-5f);
    wsf[ALPHA_OFF + idx] = al;
    float bs = bd[idx] + bd[64 + idx] + bd[128 + idx];
    wsf[BETA_OFF + idx] = beta[idx] + al * bs;
  }
}

// ------------------- K1: conv a,b + score partial accumulation -------------
// grid (n, 16-t chunk) = 1024 blocks, 256 threads, 36.2KB LDS (4 blk/CU).
// Per sub: ONE conv pass computes all 3 subsets' fa/fb (xv[8] load batches,
// 6 accumulator sets, x read once); then 3 score phases: stage ab (rows
// padded to 28), 5x5-reg-tiled scores, red2 scratch, owner-thread reduce.
__global__ __launch_bounds__(256) void k1_scores(
    const float* __restrict__ x,
    const float* __restrict__ WaT, const float* __restrict__ WbT,
    const float* __restrict__ ba, const float* __restrict__ bb,
    float* __restrict__ part)
{
  const int nb = blockIdx.x;
  const int n = nb >> 4;
  const int ch = nb & 15;
  const int tid = threadIdx.x;
  const int wave = tid >> 6;
  const int lane = tid & 63;
  const int tgrp = wave >> 1;                                     // t pair
  const int i0 = __builtin_amdgcn_readfirstlane((wave & 1) << 4); // i half
  const int tl = tgrp * 2 + lane / 25;   // local t in [0,4) (4 = inactive)
  const int tlc = tl < 4 ? tl : 3;       // clamped for address safety
  const int v = lane % 25;
  const bool act = lane < 50;

  __shared__ float ab[7168];             // a:[0,3584) b:[3584,7168), [k][28]
  __shared__ float red[1875];            // [s][625] accumulators
  float* const red2 = ab;                // [ks][625] scratch (6250<=7168)

  // scores-phase role: 25 5x5 tiles x 10 K-slices (250 threads)
  const int tp = tid % 25;
  const int ks = tid / 25;
  const int v5 = (tp / 5) * 5, w5 = (tp % 5) * 5;
  const int kb = (ks < 8) ? ks * 13 : (104 + (ks - 8) * 12);
  const int kcnt = (ks < 8) ? 13 : 12;

  for (int idx = tid; idx < 1875; idx += 256) red[idx] = 0.0f;
  __syncthreads();

#define SCORE_PHASE(S, FA, FB)                                               \
  do {                                                                       \
    __syncthreads(); /* prev phase's red2 (=ab) reads done */                \
    if (act) {                                                               \
      _Pragma("unroll")                                                      \
      for (int j = 0; j < 16; ++j) {   /* k=(i0+j)*4+tl, row stride 28 */    \
        ab[(i0 + j) * 112 + tl * 28 + v]        = FA[j];                     \
        ab[3584 + (i0 + j) * 112 + tl * 28 + v] = FB[j];                     \
      }                                                                      \
    }                                                                        \
    __syncthreads();                                                         \
    float sc[5][5];                                                          \
    if (tid < 250) {                                                         \
      _Pragma("unroll")                                                      \
      for (int dv = 0; dv < 5; ++dv)                                         \
        _Pragma("unroll")                                                    \
        for (int dw = 0; dw < 5; ++dw) sc[dv][dw] = 0.0f;                    \
      for (int kk = 0; kk < kcnt; ++kk) {                                    \
        const int k = kb + kk;                                               \
        float av[5], bv[5];                                                  \
        _Pragma("unroll")                                                    \
        for (int d = 0; d < 5; ++d) {                                        \
          av[d] = ab[k * 28 + v5 + d];                                       \
          bv[d] = ab[3584 + k * 28 + w5 + d];                                \
        }                                                                    \
        _Pragma("unroll")                                                    \
        for (int dv = 0; dv < 5; ++dv)                                       \
          _Pragma("unroll")                                                  \
          for (int dw = 0; dw < 5; ++dw)                                     \
            sc[dv][dw] = fmaf(av[dv], bv[dw], sc[dv][dw]);                   \
      }                                                                      \
    }                                                                        \
    __syncthreads(); /* ab reads done -> red2 writable */                    \
    if (tid < 250) {                                                         \
      _Pragma("unroll")                                                      \
      for (int dv = 0; dv < 5; ++dv)                                         \
        _Pragma("unroll")                                                    \
        for (int dw = 0; dw < 5; ++dw)                                       \
          red2[ks * 625 + (v5 + dv) * 25 + (w5 + dw)] = sc[dv][dw];          \
    }                                                                        \
    __syncthreads();                                                         \
    { /* owner-thread reduction over ks (atomic-free, stride-1) */           \
      float acc0 = 0.0f, acc1 = 0.0f, acc2 = 0.0f;                           \
      _Pragma("unroll")                                                      \
      for (int q = 0; q < 10; ++q) {                                         \
        acc0 += red2[q * 625 + tid];                                         \
        acc1 += red2[q * 625 + tid + 256];                                   \
        if (tid < 113) acc2 += red2[q * 625 + tid + 512];                    \
      }                                                                      \
      red[(S) * 625 + tid]        += acc0;                                   \
      red[(S) * 625 + tid + 256]  += acc1;                                   \
      if (tid < 113) red[(S) * 625 + tid + 512] += acc2;                     \
    }                                                                        \
  } while (0)

  #pragma unroll 1
  for (int sub = 0; sub < 4; ++sub) {
    const int t0 = ch * 16 + sub * 4;
    const float* xp = x + n * 409600 + (t0 + tlc) * 25 + v;
    // ---- conv: all 3 subsets in one pass, x read once ----
    float fa0[16], fa1[16], fa2[16], fb0[16], fb1[16], fb2[16];
    #pragma unroll
    for (int j = 0; j < 16; ++j) {
      fa0[j] = ba[i0 + j];      fb0[j] = bb[i0 + j];
      fa1[j] = ba[32 + i0 + j]; fb1[j] = bb[32 + i0 + j];
      fa2[j] = ba[64 + i0 + j]; fb2[j] = bb[64 + i0 + j];
    }
    const float* wa = WaT + i0;
    const float* wb = WbT + i0;
    for (int c8 = 0; c8 < 64; c8 += 8) {
      float xv[8];
      #pragma unroll
      for (int u = 0; u < 8; ++u)
        xv[u] = act ? xp[(c8 + u) * 6400] : 0.0f;
      #pragma unroll
      for (int u = 0; u < 8; ++u) {
        const int cc = (c8 + u) * 32;
        #pragma unroll
        for (int j = 0; j < 16; ++j) {
          fa0[j] = fmaf(wa[cc + j],        xv[u], fa0[j]);
          fb0[j] = fmaf(wb[cc + j],        xv[u], fb0[j]);
          fa1[j] = fmaf(wa[2048 + cc + j], xv[u], fa1[j]);
          fb1[j] = fmaf(wb[2048 + cc + j], xv[u], fb1[j]);
          fa2[j] = fmaf(wa[4096 + cc + j], xv[u], fa2[j]);
          fb2[j] = fmaf(wb[4096 + cc + j], xv[u], fb2[j]);
        }
      }
    }
    SCORE_PHASE(0, fa0, fb0);
    SCORE_PHASE(1, fa1, fb1);
    SCORE_PHASE(2, fa2, fb2);
  }
#undef SCORE_PHASE

  __syncthreads();
  for (int s = 0; s < 3; ++s)
    for (int idx = tid; idx < 625; idx += 256)
      part[((n * NCHUNK + ch) * 3 + s) * 625 + idx] = red[s * 625 + idx];
}

// -------- K2: reduce partials (coalesced), /8192, softmax(v), +A, pad -----
__global__ __launch_bounds__(256) void k2_softmax(
    const float* __restrict__ part, const float* __restrict__ A,
    float* __restrict__ att)
{
  const int ns = blockIdx.x;              // 192 = (n,s)
  const int n = ns / 3, s = ns % 3;
  const int tid = threadIdx.x;
  __shared__ float sm[625];
  for (int idx = tid; idx < 625; idx += 256) {
    float acc = 0.0f;
    #pragma unroll
    for (int chk = 0; chk < NCHUNK; ++chk)
      acc += part[((n * NCHUNK + chk) * 3 + s) * 625 + idx];  // lane-contig
    sm[idx] = acc * (1.0f / 8192.0f);
  }
  __syncthreads();
  float* ap = att + ns * 800;
  const int w = tid;
  if (w < 25) {
    float m = -3.0e38f;
    #pragma unroll
    for (int v = 0; v < 25; ++v) m = fmaxf(m, sm[v * 25 + w]);
    float e[25], sum = 0.0f;
    #pragma unroll
    for (int v = 0; v < 25; ++v) { e[v] = expf(sm[v * 25 + w] - m); sum += e[v]; }
    const float inv = 1.0f / sum;
    #pragma unroll
    for (int v = 0; v < 25; ++v)
      ap[v * 32 + w] = e[v] * inv + A[(s * 25 + v) * 25 + w];
  } else if (w < 32) {
    for (int v = 0; v < 25; ++v) ap[v * 32 + w] = 0.0f;  // pad lanes -> za=0
  }
}

// ----------------- K3: z = x@att, y += WdT@z, BN epilogue ------------------
// grid (n, t-pair) = 8192 blocks, 256 threads (R4 form: 5 blk/CU LDS cap).
// Phase A: lanes=(c,t), regs=16 w's, att row via s_load.
// Phase B: lanes=(t,w), regs=16 o's, WdT row via s_load.
__global__ __launch_bounds__(256) void k3_out(
    const float* __restrict__ x, const float* __restrict__ att,
    const float* __restrict__ WdT,
    const float* __restrict__ alpha, const float* __restrict__ betaE,
    float* __restrict__ out)
{
  const int nb = blockIdx.x;
  const int n = nb >> 7;
  const int t0 = (nb & 127) * 2;
  const int tid = threadIdx.x;
  const int wave = tid >> 6;
  const int lane = tid & 63;

  __shared__ float xs[3200];             // [c][t*25+v]  (64 x 50)
  __shared__ float zt[4224];             // [c][t*33+w]  (stride 66, pad 33)

  const float* xg = x + n * 409600 + t0 * 25;
  for (int idx = tid; idx < 3200; idx += 256) {
    int c = idx / 50, p = idx - c * 50;
    xs[idx] = xg[c * 6400 + p];
  }

  const int c0A = __builtin_amdgcn_readfirstlane((wave & 1) << 5);
  const int w0A = __builtin_amdgcn_readfirstlane((wave >> 1) << 4);
  const int o0B = __builtin_amdgcn_readfirstlane(wave << 4);
  const int tB = lane >> 5, wB = lane & 31;
  const int xbase = c0A * 50 + lane * 25;       // (c0A+lane/2, t=lane&1)
  const int zwb   = c0A * 66 + lane * 33 + w0A; // same lane mapping
  const int zrb   = tB * 33 + wB;

  float yacc[16];
  #pragma unroll
  for (int j = 0; j < 16; ++j) yacc[j] = 0.0f;

  __syncthreads();
  #pragma unroll 1
  for (int s = 0; s < 3; ++s) {
    // ---- phase A: zt[c][t][w0A..+15] = sum_v xs * att[v][w] ----
    const float* attp = att + (n * 3 + s) * 800 + w0A;
    float za[16];
    #pragma unroll
    for (int j = 0; j < 16; ++j) za[j] = 0.0f;
    #pragma unroll 5
    for (int v = 0; v < 25; ++v) {
      float xv = xs[xbase + v];
      #pragma unroll
      for (int j = 0; j < 16; ++j)
        za[j] = fmaf(attp[v * 32 + j], xv, za[j]);
    }
    #pragma unroll
    for (int j = 0; j < 16; ++j) zt[zwb + j] = za[j];
    __syncthreads();
    // ---- phase B: yacc[o0B..+15] += sum_c WdT[s][c][o] * zt[c][p] ----
    const float* wdp = WdT + s * 4096 + o0B;
    #pragma unroll 4
    for (int c = 0; c < 64; ++c) {
      float zv = zt[c * 66 + zrb];
      #pragma unroll
      for (int j = 0; j < 16; ++j)
        yacc[j] = fmaf(wdp[c * 64 + j], zv, yacc[j]);
    }
    __syncthreads();
  }
  if (wB < 25) {
    const int t = t0 + tB;
    float* op = out + n * 409600 + t * 25 + wB;
    #pragma unroll
    for (int j = 0; j < 16; ++j) {
      const int o = o0B + j;
      op[o * 6400] = alpha[o] * yacc[j] + betaE[o];
    }
  }
}

// ---------------------------------------------------------------------------
extern "C" void kernel_launch(void* const* d_in, const int* in_sizes, int n_in,
                              void* d_out, int out_size, void* d_ws, size_t ws_size,
                              hipStream_t stream) {
  const float* x     = (const float*)d_in[0];
  const float* A     = (const float*)d_in[1];
  const float* Wa    = (const float*)d_in[2];
  const float* ba    = (const float*)d_in[3];
  const float* Wb    = (const float*)d_in[4];
  const float* bb    = (const float*)d_in[5];
  const float* Wd    = (const float*)d_in[6];
  const float* bd    = (const float*)d_in[7];
  const float* gamma = (const float*)d_in[8];
  const float* beta  = (const float*)d_in[9];
  float* wsf = (float*)d_ws;
  float* out = (float*)d_out;

  k0_prep<<<64, 256, 0, stream>>>(wsf, Wa, Wb, Wd, bd, gamma, beta);
  k1_scores<<<1024, 256, 0, stream>>>(x, wsf + WAT_OFF, wsf + WBT_OFF,
                                      ba, bb, wsf + PART_OFF);
  k2_softmax<<<192, 256, 0, stream>>>(wsf + PART_OFF, A, wsf + ATT_OFF);
  k3_out<<<8192, 256, 0, stream>>>(x, wsf + ATT_OFF, wsf + WDT_OFF,
                                   wsf + ALPHA_OFF, wsf + BETA_OFF, out);
}

// Round 8
// 679.507 us; speedup vs baseline: 3.7942x; 3.7942x over previous
//
#include <hip/hip_runtime.h>

// ---------------------------------------------------------------------------
// AGCN block: a/b 1x1 convs -> scores -> softmax(+A) -> z = x@att -> y = Wd@z
// N=64 C=64 T=256 V=25 S=3 OC=64 IC=32. fp32 (no fp32 MFMA) -> VALU-bound.
// R6 post-mortem: 3-subset fused conv overflowed SGPR/VGPR files (132 VGPR,
// 12% occ, 2241us). R7: R4 conv structure (56 VGPR, proven) + occupancy play:
// no red LDS (owner-reduce writes part directly, K2 sums 64 chunks), ab
// stride 26 -> LDS 26KB -> 6 blocks/CU; chunk=4t, grid 4096.
// WS ASSUMPTION: needs ~31.4 MB of d_ws.
// ---------------------------------------------------------------------------

#define NCH       64                     // t-chunks per n in K1 (4 t each)
#define ATT_OFF   0                      // [N][S][25][32] padded att
#define ATT_SZ    (64*3*25*32)           // 153600
#define PART_OFF  153600                 // [N][NCH][S][625] score partials
#define PART_SZ   (64*NCH*3*625)         // 7680000
#define WAT_OFF   (PART_OFF + PART_SZ)   // [S][C][IC]
#define WBT_OFF   (WAT_OFF + 3*64*32)    // [S][C][IC]
#define WDT_OFF   (WBT_OFF + 3*64*32)    // [S][C][OC]
#define ALPHA_OFF (WDT_OFF + 3*64*64)    // [OC]
#define BETA_OFF  (ALPHA_OFF + 64)       // [OC]
// total ws: ~7.86M floats = 31.4 MB

// --------------------------- K0: weight prep -------------------------------
__global__ __launch_bounds__(256) void k0_prep(
    float* __restrict__ wsf,
    const float* __restrict__ Wa, const float* __restrict__ Wb,
    const float* __restrict__ Wd, const float* __restrict__ bd,
    const float* __restrict__ gamma, const float* __restrict__ beta)
{
  int idx = blockIdx.x * 256 + threadIdx.x;
  if (idx < 6144) {                       // WaT/WbT: [s][c][i] <- [s][i][c]
    int s = idx / 2048, r = idx - s * 2048, c = r >> 5, i = r & 31;
    wsf[WAT_OFF + idx] = Wa[s * 2048 + i * 64 + c];
    wsf[WBT_OFF + idx] = Wb[s * 2048 + i * 64 + c];
  }
  if (idx < 12288) {                      // WdT: [s][c][o] <- [s][o][c]
    int s = idx / 4096, r = idx - s * 4096, c = r >> 6, o = r & 63;
    wsf[WDT_OFF + idx] = Wd[s * 4096 + o * 64 + c];
  }
  if (idx < 64) {                         // fused BN(inference) + bias-sum
    float al = gamma[idx] * rsqrtf(1.0f + 1e-5f);
    wsf[ALPHA_OFF + idx] = al;
    float bs = bd[idx] + bd[64 + idx] + bd[128 + idx];
    wsf[BETA_OFF + idx] = beta[idx] + al * bs;
  }
}

// ------------------- K1: conv a,b + score partials (one 4-t chunk) ---------
// grid (n, 4-t chunk) = 64*64 = 4096 blocks, 256 threads, 26KB LDS
// (6 blk/CU). Per s: R4-style conv (xv[8] batches, fa/fb[16], s_load
// weights), stage ab rows stride 26 (<=2-way banks), 5x5-reg-tiled scores,
// red2 scratch (stride 632, aliased), owner-thread sum -> part (no LDS red).
__global__ __launch_bounds__(256, 6) void k1_scores(
    const float* __restrict__ x,
    const float* __restrict__ WaT, const float* __restrict__ WbT,
    const float* __restrict__ ba, const float* __restrict__ bb,
    float* __restrict__ part)
{
  const int nb = blockIdx.x;
  const int n = nb >> 6;
  const int ch = nb & 63;
  const int tid = threadIdx.x;
  const int wave = tid >> 6;
  const int lane = tid & 63;
  const int tgrp = wave >> 1;                                     // t pair
  const int i0 = __builtin_amdgcn_readfirstlane((wave & 1) << 4); // i half
  const int tl = tgrp * 2 + lane / 25;   // local t in [0,4) (4 = inactive)
  const int tlc = tl < 4 ? tl : 3;       // clamped for address safety
  const int v = lane % 25;
  const bool act = lane < 50;

  __shared__ float ab[6656];             // a:[0,3328) b:[3328,6656), [k][26]
  float* const red2 = ab;                // [ks][632] scratch (6320<=6656)

  // scores-phase role: 25 5x5 tiles x 10 K-slices (250 threads)
  const int tp = tid % 25;
  const int ks = tid / 25;
  const int v5 = (tp / 5) * 5, w5 = (tp % 5) * 5;
  const int kb = (ks < 8) ? ks * 13 : (104 + (ks - 8) * 12);
  const int kcnt = (ks < 8) ? 13 : 12;

  const int t0 = ch * 4;
  const float* xp = x + n * 409600 + (t0 + tlc) * 25 + v;

  #pragma unroll 1
  for (int s = 0; s < 3; ++s) {
    // ---- conv: fa/fb[16] for this lane's (t,v), 8-deep load pipeline ----
    float fa[16], fb[16];
    #pragma unroll
    for (int j = 0; j < 16; ++j) {
      fa[j] = ba[s * 32 + i0 + j];
      fb[j] = bb[s * 32 + i0 + j];
    }
    const float* wap = WaT + s * 2048 + i0;
    const float* wbp = WbT + s * 2048 + i0;
    for (int c8 = 0; c8 < 64; c8 += 8) {
      float xv[8];
      #pragma unroll
      for (int u = 0; u < 8; ++u)
        xv[u] = act ? xp[(c8 + u) * 6400] : 0.0f;
      #pragma unroll
      for (int u = 0; u < 8; ++u) {
        const float* wa8 = wap + (c8 + u) * 32;
        const float* wb8 = wbp + (c8 + u) * 32;
        #pragma unroll
        for (int j = 0; j < 16; ++j) {
          fa[j] = fmaf(wa8[j], xv[u], fa[j]);
          fb[j] = fmaf(wb8[j], xv[u], fb[j]);
        }
      }
    }
    __syncthreads();  // prev phase's red2 (=ab) reads done -> ab writable
    if (act) {
      #pragma unroll
      for (int j = 0; j < 16; ++j) {     // k = (i0+j)*4 + tl, row stride 26
        ab[(i0 + j) * 104 + tl * 26 + v]        = fa[j];
        ab[3328 + (i0 + j) * 104 + tl * 26 + v] = fb[j];
      }
    }
    __syncthreads();
    // ---- scores: sc[5][5] over this thread's K slice ----
    float sc[5][5];
    if (tid < 250) {
      #pragma unroll
      for (int dv = 0; dv < 5; ++dv)
        #pragma unroll
        for (int dw = 0; dw < 5; ++dw) sc[dv][dw] = 0.0f;
      for (int kk = 0; kk < kcnt; ++kk) {
        const int k = kb + kk;
        float av[5], bv[5];
        #pragma unroll
        for (int d = 0; d < 5; ++d) {
          av[d] = ab[k * 26 + v5 + d];
          bv[d] = ab[3328 + k * 26 + w5 + d];
        }
        #pragma unroll
        for (int dv = 0; dv < 5; ++dv)
          #pragma unroll
          for (int dw = 0; dw < 5; ++dw)
            sc[dv][dw] = fmaf(av[dv], bv[dw], sc[dv][dw]);
      }
    }
    __syncthreads();  // ab reads done -> red2 (aliased) writable
    if (tid < 250) {
      #pragma unroll
      for (int dv = 0; dv < 5; ++dv)
        #pragma unroll
        for (int dw = 0; dw < 5; ++dw)
          red2[ks * 632 + (v5 + dv) * 25 + (w5 + dw)] = sc[dv][dw];
    }
    __syncthreads();
    // ---- owner-thread reduction over ks -> straight to global part ----
    {
      float acc0 = 0.0f, acc1 = 0.0f, acc2 = 0.0f;
      #pragma unroll
      for (int q = 0; q < 10; ++q) {
        acc0 += red2[q * 632 + tid];
        acc1 += red2[q * 632 + tid + 256];
        if (tid < 113) acc2 += red2[q * 632 + tid + 512];
      }
      float* pp = part + ((n * NCH + ch) * 3 + s) * 625;
      pp[tid]       = acc0;
      pp[tid + 256] = acc1;
      if (tid < 113) pp[tid + 512] = acc2;
    }
  }
}

// -------- K2: reduce 64 chunks (coalesced), /8192, softmax(v), +A, pad ----
__global__ __launch_bounds__(256) void k2_softmax(
    const float* __restrict__ part, const float* __restrict__ A,
    float* __restrict__ att)
{
  const int ns = blockIdx.x;              // 192 = (n,s)
  const int n = ns / 3, s = ns % 3;
  const int tid = threadIdx.x;
  __shared__ float sm[625];
  for (int idx = tid; idx < 625; idx += 256) {
    float acc = 0.0f;
    #pragma unroll 8
    for (int chk = 0; chk < NCH; ++chk)
      acc += part[((n * NCH + chk) * 3 + s) * 625 + idx];  // lane-contig
    sm[idx] = acc * (1.0f / 8192.0f);
  }
  __syncthreads();
  float* ap = att + ns * 800;
  const int w = tid;
  if (w < 25) {
    float m = -3.0e38f;
    #pragma unroll
    for (int v = 0; v < 25; ++v) m = fmaxf(m, sm[v * 25 + w]);
    float e[25], sum = 0.0f;
    #pragma unroll
    for (int v = 0; v < 25; ++v) { e[v] = expf(sm[v * 25 + w] - m); sum += e[v]; }
    const float inv = 1.0f / sum;
    #pragma unroll
    for (int v = 0; v < 25; ++v)
      ap[v * 32 + w] = e[v] * inv + A[(s * 25 + v) * 25 + w];
  } else if (w < 32) {
    for (int v = 0; v < 25; ++v) ap[v * 32 + w] = 0.0f;  // pad lanes -> za=0
  }
}

// ----------------- K3: z = x@att, y += WdT@z, BN epilogue ------------------
// grid (n, t-pair) = 8192 blocks, 256 threads (R4 form: 5 blk/CU LDS cap).
// Phase A: lanes=(c,t), regs=16 w's, att row via s_load.
// Phase B: lanes=(t,w), regs=16 o's, WdT row via s_load.
__global__ __launch_bounds__(256) void k3_out(
    const float* __restrict__ x, const float* __restrict__ att,
    const float* __restrict__ WdT,
    const float* __restrict__ alpha, const float* __restrict__ betaE,
    float* __restrict__ out)
{
  const int nb = blockIdx.x;
  const int n = nb >> 7;
  const int t0 = (nb & 127) * 2;
  const int tid = threadIdx.x;
  const int wave = tid >> 6;
  const int lane = tid & 63;

  __shared__ float xs[3200];             // [c][t*25+v]  (64 x 50)
  __shared__ float zt[4224];             // [c][t*33+w]  (stride 66, pad 33)

  const float* xg = x + n * 409600 + t0 * 25;
  for (int idx = tid; idx < 3200; idx += 256) {
    int c = idx / 50, p = idx - c * 50;
    xs[idx] = xg[c * 6400 + p];
  }

  const int c0A = __builtin_amdgcn_readfirstlane((wave & 1) << 5);
  const int w0A = __builtin_amdgcn_readfirstlane((wave >> 1) << 4);
  const int o0B = __builtin_amdgcn_readfirstlane(wave << 4);
  const int tB = lane >> 5, wB = lane & 31;
  const int xbase = c0A * 50 + lane * 25;       // (c0A+lane/2, t=lane&1)
  const int zwb   = c0A * 66 + lane * 33 + w0A; // same lane mapping
  const int zrb   = tB * 33 + wB;

  float yacc[16];
  #pragma unroll
  for (int j = 0; j < 16; ++j) yacc[j] = 0.0f;

  __syncthreads();
  #pragma unroll 1
  for (int s = 0; s < 3; ++s) {
    // ---- phase A: zt[c][t][w0A..+15] = sum_v xs * att[v][w] ----
    const float* attp = att + (n * 3 + s) * 800 + w0A;
    float za[16];
    #pragma unroll
    for (int j = 0; j < 16; ++j) za[j] = 0.0f;
    #pragma unroll 5
    for (int v = 0; v < 25; ++v) {
      float xv = xs[xbase + v];
      #pragma unroll
      for (int j = 0; j < 16; ++j)
        za[j] = fmaf(attp[v * 32 + j], xv, za[j]);
    }
    #pragma unroll
    for (int j = 0; j < 16; ++j) zt[zwb + j] = za[j];
    __syncthreads();
    // ---- phase B: yacc[o0B..+15] += sum_c WdT[s][c][o] * zt[c][p] ----
    const float* wdp = WdT + s * 4096 + o0B;
    #pragma unroll 4
    for (int c = 0; c < 64; ++c) {
      float zv = zt[c * 66 + zrb];
      #pragma unroll
      for (int j = 0; j < 16; ++j)
        yacc[j] = fmaf(wdp[c * 64 + j], zv, yacc[j]);
    }
    __syncthreads();
  }
  if (wB < 25) {
    const int t = t0 + tB;
    float* op = out + n * 409600 + t * 25 + wB;
    #pragma unroll
    for (int j = 0; j < 16; ++j) {
      const int o = o0B + j;
      op[o * 6400] = alpha[o] * yacc[j] + betaE[o];
    }
  }
}

// ---------------------------------------------------------------------------
extern "C" void kernel_launch(void* const* d_in, const int* in_sizes, int n_in,
                              void* d_out, int out_size, void* d_ws, size_t ws_size,
                              hipStream_t stream) {
  const float* x     = (const float*)d_in[0];
  const float* A     = (const float*)d_in[1];
  const float* Wa    = (const float*)d_in[2];
  const float* ba    = (const float*)d_in[3];
  const float* Wb    = (const float*)d_in[4];
  const float* bb    = (const float*)d_in[5];
  const float* Wd    = (const float*)d_in[6];
  const float* bd    = (const float*)d_in[7];
  const float* gamma = (const float*)d_in[8];
  const float* beta  = (const float*)d_in[9];
  float* wsf = (float*)d_ws;
  float* out = (float*)d_out;

  k0_prep<<<64, 256, 0, stream>>>(wsf, Wa, Wb, Wd, bd, gamma, beta);
  k1_scores<<<4096, 256, 0, stream>>>(x, wsf + WAT_OFF, wsf + WBT_OFF,
                                      ba, bb, wsf + PART_OFF);
  k2_softmax<<<192, 256, 0, stream>>>(wsf + PART_OFF, A, wsf + ATT_OFF);
  k3_out<<<8192, 256, 0, stream>>>(x, wsf + ATT_OFF, wsf + WDT_OFF,
                                   wsf + ALPHA_OFF, wsf + BETA_OFF, out);
}

// Round 9
// 561.777 us; speedup vs baseline: 4.5894x; 1.2096x over previous
//
#include <hip/hip_runtime.h>

// ---------------------------------------------------------------------------
// AGCN block: a/b 1x1 convs -> scores -> softmax(+A) -> z = x@att -> y = Wd@z
// N=64 C=64 T=256 V=25 S=3 OC=64 IC=32. fp32 (no fp32 MFMA) -> VALU-bound.
// R8 post-mortem: __launch_bounds__(256,6) forced VGPR=40 -> spilled fa/fb/xv
// (FETCH 113->242MB = scratch), VALU 46%, K1 321us. R9: drop the min-waves
// clamp (R4 evidence: unclamped = 56 VGPR, no spill); LDS diet (26.6KB)
// still allows 6 blk/CU. Single-variable change vs R8.
// WS ASSUMPTION: needs ~31.4 MB of d_ws.
// ---------------------------------------------------------------------------

#define NCH       64                     // t-chunks per n in K1 (4 t each)
#define ATT_OFF   0                      // [N][S][25][32] padded att
#define ATT_SZ    (64*3*25*32)           // 153600
#define PART_OFF  153600                 // [N][NCH][S][625] score partials
#define PART_SZ   (64*NCH*3*625)         // 7680000
#define WAT_OFF   (PART_OFF + PART_SZ)   // [S][C][IC]
#define WBT_OFF   (WAT_OFF + 3*64*32)    // [S][C][IC]
#define WDT_OFF   (WBT_OFF + 3*64*32)    // [S][C][OC]
#define ALPHA_OFF (WDT_OFF + 3*64*64)    // [OC]
#define BETA_OFF  (ALPHA_OFF + 64)       // [OC]
// total ws: ~7.86M floats = 31.4 MB

// --------------------------- K0: weight prep -------------------------------
__global__ __launch_bounds__(256) void k0_prep(
    float* __restrict__ wsf,
    const float* __restrict__ Wa, const float* __restrict__ Wb,
    const float* __restrict__ Wd, const float* __restrict__ bd,
    const float* __restrict__ gamma, const float* __restrict__ beta)
{
  int idx = blockIdx.x * 256 + threadIdx.x;
  if (idx < 6144) {                       // WaT/WbT: [s][c][i] <- [s][i][c]
    int s = idx / 2048, r = idx - s * 2048, c = r >> 5, i = r & 31;
    wsf[WAT_OFF + idx] = Wa[s * 2048 + i * 64 + c];
    wsf[WBT_OFF + idx] = Wb[s * 2048 + i * 64 + c];
  }
  if (idx < 12288) {                      // WdT: [s][c][o] <- [s][o][c]
    int s = idx / 4096, r = idx - s * 4096, c = r >> 6, o = r & 63;
    wsf[WDT_OFF + idx] = Wd[s * 4096 + o * 64 + c];
  }
  if (idx < 64) {                         // fused BN(inference) + bias-sum
    float al = gamma[idx] * rsqrtf(1.0f + 1e-5f);
    wsf[ALPHA_OFF + idx] = al;
    float bs = bd[idx] + bd[64 + idx] + bd[128 + idx];
    wsf[BETA_OFF + idx] = beta[idx] + al * bs;
  }
}

// ------------------- K1: conv a,b + score partials (one 4-t chunk) ---------
// grid (n, 4-t chunk) = 64*64 = 4096 blocks, 256 threads, 26KB LDS
// (6 blk/CU by LDS; VGPR free to land ~56 like R4 -> no spill).
// Per s: conv (xv[8] batches, fa/fb[16], s_load weights), stage ab rows
// stride 26 (<=2-way banks), 5x5-reg-tiled scores, red2 scratch (stride 632,
// aliased), owner-thread sum -> part (no LDS red).
__global__ __launch_bounds__(256) void k1_scores(
    const float* __restrict__ x,
    const float* __restrict__ WaT, const float* __restrict__ WbT,
    const float* __restrict__ ba, const float* __restrict__ bb,
    float* __restrict__ part)
{
  const int nb = blockIdx.x;
  const int n = nb >> 6;
  const int ch = nb & 63;
  const int tid = threadIdx.x;
  const int wave = tid >> 6;
  const int lane = tid & 63;
  const int tgrp = wave >> 1;                                     // t pair
  const int i0 = __builtin_amdgcn_readfirstlane((wave & 1) << 4); // i half
  const int tl = tgrp * 2 + lane / 25;   // local t in [0,4) (4 = inactive)
  const int tlc = tl < 4 ? tl : 3;       // clamped for address safety
  const int v = lane % 25;
  const bool act = lane < 50;

  __shared__ float ab[6656];             // a:[0,3328) b:[3328,6656), [k][26]
  float* const red2 = ab;                // [ks][632] scratch (6320<=6656)

  // scores-phase role: 25 5x5 tiles x 10 K-slices (250 threads)
  const int tp = tid % 25;
  const int ks = tid / 25;
  const int v5 = (tp / 5) * 5, w5 = (tp % 5) * 5;
  const int kb = (ks < 8) ? ks * 13 : (104 + (ks - 8) * 12);
  const int kcnt = (ks < 8) ? 13 : 12;

  const int t0 = ch * 4;
  const float* xp = x + n * 409600 + (t0 + tlc) * 25 + v;

  #pragma unroll 1
  for (int s = 0; s < 3; ++s) {
    // ---- conv: fa/fb[16] for this lane's (t,v), 8-deep load pipeline ----
    float fa[16], fb[16];
    #pragma unroll
    for (int j = 0; j < 16; ++j) {
      fa[j] = ba[s * 32 + i0 + j];
      fb[j] = bb[s * 32 + i0 + j];
    }
    const float* wap = WaT + s * 2048 + i0;
    const float* wbp = WbT + s * 2048 + i0;
    for (int c8 = 0; c8 < 64; c8 += 8) {
      float xv[8];
      #pragma unroll
      for (int u = 0; u < 8; ++u)
        xv[u] = act ? xp[(c8 + u) * 6400] : 0.0f;
      #pragma unroll
      for (int u = 0; u < 8; ++u) {
        const float* wa8 = wap + (c8 + u) * 32;
        const float* wb8 = wbp + (c8 + u) * 32;
        #pragma unroll
        for (int j = 0; j < 16; ++j) {
          fa[j] = fmaf(wa8[j], xv[u], fa[j]);
          fb[j] = fmaf(wb8[j], xv[u], fb[j]);
        }
      }
    }
    __syncthreads();  // prev phase's red2 (=ab) reads done -> ab writable
    if (act) {
      #pragma unroll
      for (int j = 0; j < 16; ++j) {     // k = (i0+j)*4 + tl, row stride 26
        ab[(i0 + j) * 104 + tl * 26 + v]        = fa[j];
        ab[3328 + (i0 + j) * 104 + tl * 26 + v] = fb[j];
      }
    }
    __syncthreads();
    // ---- scores: sc[5][5] over this thread's K slice ----
    float sc[5][5];
    if (tid < 250) {
      #pragma unroll
      for (int dv = 0; dv < 5; ++dv)
        #pragma unroll
        for (int dw = 0; dw < 5; ++dw) sc[dv][dw] = 0.0f;
      for (int kk = 0; kk < kcnt; ++kk) {
        const int k = kb + kk;
        float av[5], bv[5];
        #pragma unroll
        for (int d = 0; d < 5; ++d) {
          av[d] = ab[k * 26 + v5 + d];
          bv[d] = ab[3328 + k * 26 + w5 + d];
        }
        #pragma unroll
        for (int dv = 0; dv < 5; ++dv)
          #pragma unroll
          for (int dw = 0; dw < 5; ++dw)
            sc[dv][dw] = fmaf(av[dv], bv[dw], sc[dv][dw]);
      }
    }
    __syncthreads();  // ab reads done -> red2 (aliased) writable
    if (tid < 250) {
      #pragma unroll
      for (int dv = 0; dv < 5; ++dv)
        #pragma unroll
        for (int dw = 0; dw < 5; ++dw)
          red2[ks * 632 + (v5 + dv) * 25 + (w5 + dw)] = sc[dv][dw];
    }
    __syncthreads();
    // ---- owner-thread reduction over ks -> straight to global part ----
    {
      float acc0 = 0.0f, acc1 = 0.0f, acc2 = 0.0f;
      #pragma unroll
      for (int q = 0; q < 10; ++q) {
        acc0 += red2[q * 632 + tid];
        acc1 += red2[q * 632 + tid + 256];
        if (tid < 113) acc2 += red2[q * 632 + tid + 512];
      }
      float* pp = part + ((n * NCH + ch) * 3 + s) * 625;
      pp[tid]       = acc0;
      pp[tid + 256] = acc1;
      if (tid < 113) pp[tid + 512] = acc2;
    }
  }
}

// -------- K2: reduce 64 chunks (coalesced), /8192, softmax(v), +A, pad ----
__global__ __launch_bounds__(256) void k2_softmax(
    const float* __restrict__ part, const float* __restrict__ A,
    float* __restrict__ att)
{
  const int ns = blockIdx.x;              // 192 = (n,s)
  const int n = ns / 3, s = ns % 3;
  const int tid = threadIdx.x;
  __shared__ float sm[625];
  for (int idx = tid; idx < 625; idx += 256) {
    float acc = 0.0f;
    #pragma unroll 8
    for (int chk = 0; chk < NCH; ++chk)
      acc += part[((n * NCH + chk) * 3 + s) * 625 + idx];  // lane-contig
    sm[idx] = acc * (1.0f / 8192.0f);
  }
  __syncthreads();
  float* ap = att + ns * 800;
  const int w = tid;
  if (w < 25) {
    float m = -3.0e38f;
    #pragma unroll
    for (int v = 0; v < 25; ++v) m = fmaxf(m, sm[v * 25 + w]);
    float e[25], sum = 0.0f;
    #pragma unroll
    for (int v = 0; v < 25; ++v) { e[v] = expf(sm[v * 25 + w] - m); sum += e[v]; }
    const float inv = 1.0f / sum;
    #pragma unroll
    for (int v = 0; v < 25; ++v)
      ap[v * 32 + w] = e[v] * inv + A[(s * 25 + v) * 25 + w];
  } else if (w < 32) {
    for (int v = 0; v < 25; ++v) ap[v * 32 + w] = 0.0f;  // pad lanes -> za=0
  }
}

// ----------------- K3: z = x@att, y += WdT@z, BN epilogue ------------------
// grid (n, t-pair) = 8192 blocks, 256 threads (R4 form: 5 blk/CU LDS cap).
// Phase A: lanes=(c,t), regs=16 w's, att row via s_load.
// Phase B: lanes=(t,w), regs=16 o's, WdT row via s_load.
__global__ __launch_bounds__(256) void k3_out(
    const float* __restrict__ x, const float* __restrict__ att,
    const float* __restrict__ WdT,
    const float* __restrict__ alpha, const float* __restrict__ betaE,
    float* __restrict__ out)
{
  const int nb = blockIdx.x;
  const int n = nb >> 7;
  const int t0 = (nb & 127) * 2;
  const int tid = threadIdx.x;
  const int wave = tid >> 6;
  const int lane = tid & 63;

  __shared__ float xs[3200];             // [c][t*25+v]  (64 x 50)
  __shared__ float zt[4224];             // [c][t*33+w]  (stride 66, pad 33)

  const float* xg = x + n * 409600 + t0 * 25;
  for (int idx = tid; idx < 3200; idx += 256) {
    int c = idx / 50, p = idx - c * 50;
    xs[idx] = xg[c * 6400 + p];
  }

  const int c0A = __builtin_amdgcn_readfirstlane((wave & 1) << 5);
  const int w0A = __builtin_amdgcn_readfirstlane((wave >> 1) << 4);
  const int o0B = __builtin_amdgcn_readfirstlane(wave << 4);
  const int tB = lane >> 5, wB = lane & 31;
  const int xbase = c0A * 50 + lane * 25;       // (c0A+lane/2, t=lane&1)
  const int zwb   = c0A * 66 + lane * 33 + w0A; // same lane mapping
  const int zrb   = tB * 33 + wB;

  float yacc[16];
  #pragma unroll
  for (int j = 0; j < 16; ++j) yacc[j] = 0.0f;

  __syncthreads();
  #pragma unroll 1
  for (int s = 0; s < 3; ++s) {
    // ---- phase A: zt[c][t][w0A..+15] = sum_v xs * att[v][w] ----
    const float* attp = att + (n * 3 + s) * 800 + w0A;
    float za[16];
    #pragma unroll
    for (int j = 0; j < 16; ++j) za[j] = 0.0f;
    #pragma unroll 5
    for (int v = 0; v < 25; ++v) {
      float xv = xs[xbase + v];
      #pragma unroll
      for (int j = 0; j < 16; ++j)
        za[j] = fmaf(attp[v * 32 + j], xv, za[j]);
    }
    #pragma unroll
    for (int j = 0; j < 16; ++j) zt[zwb + j] = za[j];
    __syncthreads();
    // ---- phase B: yacc[o0B..+15] += sum_c WdT[s][c][o] * zt[c][p] ----
    const float* wdp = WdT + s * 4096 + o0B;
    #pragma unroll 4
    for (int c = 0; c < 64; ++c) {
      float zv = zt[c * 66 + zrb];
      #pragma unroll
      for (int j = 0; j < 16; ++j)
        yacc[j] = fmaf(wdp[c * 64 + j], zv, yacc[j]);
    }
    __syncthreads();
  }
  if (wB < 25) {
    const int t = t0 + tB;
    float* op = out + n * 409600 + t * 25 + wB;
    #pragma unroll
    for (int j = 0; j < 16; ++j) {
      const int o = o0B + j;
      op[o * 6400] = alpha[o] * yacc[j] + betaE[o];
    }
  }
}

// ---------------------------------------------------------------------------
extern "C" void kernel_launch(void* const* d_in, const int* in_sizes, int n_in,
                              void* d_out, int out_size, void* d_ws, size_t ws_size,
                              hipStream_t stream) {
  const float* x     = (const float*)d_in[0];
  const float* A     = (const float*)d_in[1];
  const float* Wa    = (const float*)d_in[2];
  const float* ba    = (const float*)d_in[3];
  const float* Wb    = (const float*)d_in[4];
  const float* bb    = (const float*)d_in[5];
  const float* Wd    = (const float*)d_in[6];
  const float* bd    = (const float*)d_in[7];
  const float* gamma = (const float*)d_in[8];
  const float* beta  = (const float*)d_in[9];
  float* wsf = (float*)d_ws;
  float* out = (float*)d_out;

  k0_prep<<<64, 256, 0, stream>>>(wsf, Wa, Wb, Wd, bd, gamma, beta);
  k1_scores<<<4096, 256, 0, stream>>>(x, wsf + WAT_OFF, wsf + WBT_OFF,
                                      ba, bb, wsf + PART_OFF);
  k2_softmax<<<192, 256, 0, stream>>>(wsf + PART_OFF, A, wsf + ATT_OFF);
  k3_out<<<8192, 256, 0, stream>>>(x, wsf + ATT_OFF, wsf + WDT_OFF,
                                   wsf + ALPHA_OFF, wsf + BETA_OFF, out);
}

// Round 10
// 555.906 us; speedup vs baseline: 4.6378x; 1.0106x over previous
//
#include <hip/hip_runtime.h>

// ---------------------------------------------------------------------------
// AGCN block: a/b 1x1 convs -> scores -> softmax(+A) -> z = x@att -> y = Wd@z
// N=64 C=64 T=256 V=25 S=3 OC=64 IC=32. fp32 (no fp32 MFMA) -> VALU-bound.
// R9 post-mortem: spill fixed (de-clamp), total 562us; K3 now top (236us,
// occ 51% capped by LDS 29.7KB). R10: K3 drops xs staging (x -> xreg[25]
// from global, rows read by only 2 lanes -> L1 dedup), LDS 16.9KB ->
// 7-8 blk/CU; K2 1024 threads (latency-bound at 192 small blocks).
// WS ASSUMPTION: needs ~31.4 MB of d_ws.
// ---------------------------------------------------------------------------

#define NCH       64                     // t-chunks per n in K1 (4 t each)
#define ATT_OFF   0                      // [N][S][25][32] padded att
#define ATT_SZ    (64*3*25*32)           // 153600
#define PART_OFF  153600                 // [N][NCH][S][625] score partials
#define PART_SZ   (64*NCH*3*625)         // 7680000
#define WAT_OFF   (PART_OFF + PART_SZ)   // [S][C][IC]
#define WBT_OFF   (WAT_OFF + 3*64*32)    // [S][C][IC]
#define WDT_OFF   (WBT_OFF + 3*64*32)    // [S][C][OC]
#define ALPHA_OFF (WDT_OFF + 3*64*64)    // [OC]
#define BETA_OFF  (ALPHA_OFF + 64)       // [OC]
// total ws: ~7.86M floats = 31.4 MB

// --------------------------- K0: weight prep -------------------------------
__global__ __launch_bounds__(256) void k0_prep(
    float* __restrict__ wsf,
    const float* __restrict__ Wa, const float* __restrict__ Wb,
    const float* __restrict__ Wd, const float* __restrict__ bd,
    const float* __restrict__ gamma, const float* __restrict__ beta)
{
  int idx = blockIdx.x * 256 + threadIdx.x;
  if (idx < 6144) {                       // WaT/WbT: [s][c][i] <- [s][i][c]
    int s = idx / 2048, r = idx - s * 2048, c = r >> 5, i = r & 31;
    wsf[WAT_OFF + idx] = Wa[s * 2048 + i * 64 + c];
    wsf[WBT_OFF + idx] = Wb[s * 2048 + i * 64 + c];
  }
  if (idx < 12288) {                      // WdT: [s][c][o] <- [s][o][c]
    int s = idx / 4096, r = idx - s * 4096, c = r >> 6, o = r & 63;
    wsf[WDT_OFF + idx] = Wd[s * 4096 + o * 64 + c];
  }
  if (idx < 64) {                         // fused BN(inference) + bias-sum
    float al = gamma[idx] * rsqrtf(1.0f + 1e-5f);
    wsf[ALPHA_OFF + idx] = al;
    float bs = bd[idx] + bd[64 + idx] + bd[128 + idx];
    wsf[BETA_OFF + idx] = beta[idx] + al * bs;
  }
}

// ------------------- K1: conv a,b + score partials (one 4-t chunk) ---------
// grid (n, 4-t chunk) = 64*64 = 4096 blocks, 256 threads, 26KB LDS.
// Unclamped (R9-proven). Per s: conv (xv[8] batches, fa/fb[16], s_load
// weights), stage ab rows stride 26, 5x5-reg-tiled scores, red2 scratch,
// owner-thread sum -> part.
__global__ __launch_bounds__(256) void k1_scores(
    const float* __restrict__ x,
    const float* __restrict__ WaT, const float* __restrict__ WbT,
    const float* __restrict__ ba, const float* __restrict__ bb,
    float* __restrict__ part)
{
  const int nb = blockIdx.x;
  const int n = nb >> 6;
  const int ch = nb & 63;
  const int tid = threadIdx.x;
  const int wave = tid >> 6;
  const int lane = tid & 63;
  const int tgrp = wave >> 1;                                     // t pair
  const int i0 = __builtin_amdgcn_readfirstlane((wave & 1) << 4); // i half
  const int tl = tgrp * 2 + lane / 25;   // local t in [0,4) (4 = inactive)
  const int tlc = tl < 4 ? tl : 3;       // clamped for address safety
  const int v = lane % 25;
  const bool act = lane < 50;

  __shared__ float ab[6656];             // a:[0,3328) b:[3328,6656), [k][26]
  float* const red2 = ab;                // [ks][632] scratch (6320<=6656)

  // scores-phase role: 25 5x5 tiles x 10 K-slices (250 threads)
  const int tp = tid % 25;
  const int ks = tid / 25;
  const int v5 = (tp / 5) * 5, w5 = (tp % 5) * 5;
  const int kb = (ks < 8) ? ks * 13 : (104 + (ks - 8) * 12);
  const int kcnt = (ks < 8) ? 13 : 12;

  const int t0 = ch * 4;
  const float* xp = x + n * 409600 + (t0 + tlc) * 25 + v;

  #pragma unroll 1
  for (int s = 0; s < 3; ++s) {
    // ---- conv: fa/fb[16] for this lane's (t,v), 8-deep load pipeline ----
    float fa[16], fb[16];
    #pragma unroll
    for (int j = 0; j < 16; ++j) {
      fa[j] = ba[s * 32 + i0 + j];
      fb[j] = bb[s * 32 + i0 + j];
    }
    const float* wap = WaT + s * 2048 + i0;
    const float* wbp = WbT + s * 2048 + i0;
    for (int c8 = 0; c8 < 64; c8 += 8) {
      float xv[8];
      #pragma unroll
      for (int u = 0; u < 8; ++u)
        xv[u] = act ? xp[(c8 + u) * 6400] : 0.0f;
      #pragma unroll
      for (int u = 0; u < 8; ++u) {
        const float* wa8 = wap + (c8 + u) * 32;
        const float* wb8 = wbp + (c8 + u) * 32;
        #pragma unroll
        for (int j = 0; j < 16; ++j) {
          fa[j] = fmaf(wa8[j], xv[u], fa[j]);
          fb[j] = fmaf(wb8[j], xv[u], fb[j]);
        }
      }
    }
    __syncthreads();  // prev phase's red2 (=ab) reads done -> ab writable
    if (act) {
      #pragma unroll
      for (int j = 0; j < 16; ++j) {     // k = (i0+j)*4 + tl, row stride 26
        ab[(i0 + j) * 104 + tl * 26 + v]        = fa[j];
        ab[3328 + (i0 + j) * 104 + tl * 26 + v] = fb[j];
      }
    }
    __syncthreads();
    // ---- scores: sc[5][5] over this thread's K slice ----
    float sc[5][5];
    if (tid < 250) {
      #pragma unroll
      for (int dv = 0; dv < 5; ++dv)
        #pragma unroll
        for (int dw = 0; dw < 5; ++dw) sc[dv][dw] = 0.0f;
      for (int kk = 0; kk < kcnt; ++kk) {
        const int k = kb + kk;
        float av[5], bv[5];
        #pragma unroll
        for (int d = 0; d < 5; ++d) {
          av[d] = ab[k * 26 + v5 + d];
          bv[d] = ab[3328 + k * 26 + w5 + d];
        }
        #pragma unroll
        for (int dv = 0; dv < 5; ++dv)
          #pragma unroll
          for (int dw = 0; dw < 5; ++dw)
            sc[dv][dw] = fmaf(av[dv], bv[dw], sc[dv][dw]);
      }
    }
    __syncthreads();  // ab reads done -> red2 (aliased) writable
    if (tid < 250) {
      #pragma unroll
      for (int dv = 0; dv < 5; ++dv)
        #pragma unroll
        for (int dw = 0; dw < 5; ++dw)
          red2[ks * 632 + (v5 + dv) * 25 + (w5 + dw)] = sc[dv][dw];
    }
    __syncthreads();
    // ---- owner-thread reduction over ks -> straight to global part ----
    {
      float acc0 = 0.0f, acc1 = 0.0f, acc2 = 0.0f;
      #pragma unroll
      for (int q = 0; q < 10; ++q) {
        acc0 += red2[q * 632 + tid];
        acc1 += red2[q * 632 + tid + 256];
        if (tid < 113) acc2 += red2[q * 632 + tid + 512];
      }
      float* pp = part + ((n * NCH + ch) * 3 + s) * 625;
      pp[tid]       = acc0;
      pp[tid + 256] = acc1;
      if (tid < 113) pp[tid + 512] = acc2;
    }
  }
}

// -------- K2: reduce 64 chunks (coalesced), /8192, softmax(v), +A, pad ----
// 1024 threads: 192 blocks are <1/CU, latency-bound -> 4x loads in flight.
__global__ __launch_bounds__(1024) void k2_softmax(
    const float* __restrict__ part, const float* __restrict__ A,
    float* __restrict__ att)
{
  const int ns = blockIdx.x;              // 192 = (n,s)
  const int n = ns / 3, s = ns % 3;
  const int tid = threadIdx.x;
  __shared__ float sm[625];
  for (int idx = tid; idx < 625; idx += 1024) {
    float acc = 0.0f;
    #pragma unroll 8
    for (int chk = 0; chk < NCH; ++chk)
      acc += part[((n * NCH + chk) * 3 + s) * 625 + idx];  // lane-contig
    sm[idx] = acc * (1.0f / 8192.0f);
  }
  __syncthreads();
  float* ap = att + ns * 800;
  const int w = tid;
  if (w < 25) {
    float m = -3.0e38f;
    #pragma unroll
    for (int v = 0; v < 25; ++v) m = fmaxf(m, sm[v * 25 + w]);
    float e[25], sum = 0.0f;
    #pragma unroll
    for (int v = 0; v < 25; ++v) { e[v] = expf(sm[v * 25 + w] - m); sum += e[v]; }
    const float inv = 1.0f / sum;
    #pragma unroll
    for (int v = 0; v < 25; ++v)
      ap[v * 32 + w] = e[v] * inv + A[(s * 25 + v) * 25 + w];
  } else if (w < 32) {
    for (int v = 0; v < 25; ++v) ap[v * 32 + w] = 0.0f;  // pad lanes -> za=0
  }
}

// ----------------- K3: z = x@att, y += WdT@z, BN epilogue ------------------
// grid (n, t-pair) = 8192 blocks, 256 threads. NO xs staging: each phase-A
// lane holds its (c,t) x row in xreg[25] (loaded from global once; each row
// fetched by only 2 lanes -> L1 dedup). LDS = zt only (16.9KB) -> 7-8 blk/CU.
// Phase A: lanes=(c,t), regs=16 w's, att row via s_load.
// Phase B: lanes=(t,w), regs=16 o's, WdT row via s_load.
__global__ __launch_bounds__(256) void k3_out(
    const float* __restrict__ x, const float* __restrict__ att,
    const float* __restrict__ WdT,
    const float* __restrict__ alpha, const float* __restrict__ betaE,
    float* __restrict__ out)
{
  const int nb = blockIdx.x;
  const int n = nb >> 7;
  const int t0 = (nb & 127) * 2;
  const int tid = threadIdx.x;
  const int wave = tid >> 6;
  const int lane = tid & 63;

  __shared__ float zt[4224];             // [c][t*33+w]  (stride 66, pad 33)

  const int c0A = __builtin_amdgcn_readfirstlane((wave & 1) << 5);
  const int w0A = __builtin_amdgcn_readfirstlane((wave >> 1) << 4);
  const int o0B = __builtin_amdgcn_readfirstlane(wave << 4);
  const int tB = lane >> 5, wB = lane & 31;
  const int cA = c0A + (lane >> 1);             // phase-A lane's c
  const int tA = lane & 1;                      // phase-A lane's t
  const int zwb = cA * 66 + tA * 33 + w0A;
  const int zrb = tB * 33 + wB;

  // this lane's x row: x[n, cA, t0+tA, 0..24], held across all 3 s
  const float* xg = x + n * 409600 + cA * 6400 + (t0 + tA) * 25;
  float xreg[25];
  #pragma unroll
  for (int v = 0; v < 25; ++v) xreg[v] = xg[v];

  float yacc[16];
  #pragma unroll
  for (int j = 0; j < 16; ++j) yacc[j] = 0.0f;

  #pragma unroll 1
  for (int s = 0; s < 3; ++s) {
    // ---- phase A: zt[c][t][w0A..+15] = sum_v xreg * att[v][w] ----
    const float* attp = att + (n * 3 + s) * 800 + w0A;
    float za[16];
    #pragma unroll
    for (int j = 0; j < 16; ++j) za[j] = 0.0f;
    #pragma unroll
    for (int v = 0; v < 25; ++v) {
      #pragma unroll
      for (int j = 0; j < 16; ++j)
        za[j] = fmaf(attp[v * 32 + j], xreg[v], za[j]);
    }
    #pragma unroll
    for (int j = 0; j < 16; ++j) zt[zwb + j] = za[j];
    __syncthreads();
    // ---- phase B: yacc[o0B..+15] += sum_c WdT[s][c][o] * zt[c][p] ----
    const float* wdp = WdT + s * 4096 + o0B;
    #pragma unroll 4
    for (int c = 0; c < 64; ++c) {
      float zv = zt[c * 66 + zrb];
      #pragma unroll
      for (int j = 0; j < 16; ++j)
        yacc[j] = fmaf(wdp[c * 64 + j], zv, yacc[j]);
    }
    __syncthreads();
  }
  if (wB < 25) {
    const int t = t0 + tB;
    float* op = out + n * 409600 + t * 25 + wB;
    #pragma unroll
    for (int j = 0; j < 16; ++j) {
      const int o = o0B + j;
      op[o * 6400] = alpha[o] * yacc[j] + betaE[o];
    }
  }
}

// ---------------------------------------------------------------------------
extern "C" void kernel_launch(void* const* d_in, const int* in_sizes, int n_in,
                              void* d_out, int out_size, void* d_ws, size_t ws_size,
                              hipStream_t stream) {
  const float* x     = (const float*)d_in[0];
  const float* A     = (const float*)d_in[1];
  const float* Wa    = (const float*)d_in[2];
  const float* ba    = (const float*)d_in[3];
  const float* Wb    = (const float*)d_in[4];
  const float* bb    = (const float*)d_in[5];
  const float* Wd    = (const float*)d_in[6];
  const float* bd    = (const float*)d_in[7];
  const float* gamma = (const float*)d_in[8];
  const float* beta  = (const float*)d_in[9];
  float* wsf = (float*)d_ws;
  float* out = (float*)d_out;

  k0_prep<<<64, 256, 0, stream>>>(wsf, Wa, Wb, Wd, bd, gamma, beta);
  k1_scores<<<4096, 256, 0, stream>>>(x, wsf + WAT_OFF, wsf + WBT_OFF,
                                      ba, bb, wsf + PART_OFF);
  k2_softmax<<<192, 1024, 0, stream>>>(wsf + PART_OFF, A, wsf + ATT_OFF);
  k3_out<<<8192, 256, 0, stream>>>(x, wsf + ATT_OFF, wsf + WDT_OFF,
                                   wsf + ALPHA_OFF, wsf + BETA_OFF, out);
}